// Round 16
// baseline (5373.408 us; speedup 1.0000x reference)
//
#include <hip/hip_runtime.h>
#include <hip/hip_bf16.h>
#include <math.h>

#define DEV __device__ __forceinline__

typedef __bf16 bf16x8 __attribute__((ext_vector_type(8)));
typedef float f32x4 __attribute__((ext_vector_type(4)));
typedef unsigned short u16x8 __attribute__((ext_vector_type(8)));
typedef unsigned short u16x4 __attribute__((ext_vector_type(4)));

DEV float b2f(unsigned short u){ unsigned int i = ((unsigned int)u)<<16; float f; __builtin_memcpy(&f,&i,4); return f; }
DEV unsigned short f2b(float x){ unsigned int i; __builtin_memcpy(&i,&x,4); unsigned int r = i + 0x7FFFu + ((i>>16)&1u); return (unsigned short)(r>>16); }

// XOR-swizzled element index within a [rows][64] u16 plane (16B-unit swizzle).
DEV int swz(int row, int elem){ return row*64 + ((((elem>>3) ^ row) & 7)<<3) + (elem&7); }

// bijective XCD-chunk swizzle (m204)
DEV int xcd_swz(int orig, int nwg){
  int q = nwg >> 3, r = nwg & 7;
  int x = orig & 7, idx = orig >> 3;
  return (x < r ? x*(q+1) : r*(q+1) + (x-r)*q) + idx;
}

enum { EPI_F32=0, EPI_GELU=2, EPI_RESF32=3 };

// ---------------------------------------------------------------- 256xBN bf16 GEMM, reg-staged 1-deep
// NRB: B-fragments per wave; BN = NRB*64. NRB=2 -> 48KB LDS -> 3 blocks/CU (TLP).
template<int NRB>
__global__ __launch_bounds__(512)
void gemm3(const unsigned short* __restrict__ A, const unsigned short* __restrict__ Bt,
           const float* __restrict__ bias, unsigned short* __restrict__ Out,
           int M, int N, int K, int NT)
{
    constexpr int BN = NRB*64;
    __shared__ unsigned short As[256*64];
    __shared__ unsigned short Bs[BN*64];
    const int tid  = threadIdx.x;
    const int lane = tid & 63;
    const int wave = tid >> 6;
    const int wr = wave >> 2, wc = wave & 3;   // 2 x 4 wave grid
    const int nb = xcd_swz(blockIdx.x, gridDim.x);
    const int nt = nb % NT, mt = nb / NT;

    f32x4 acc[8][NRB];
    #pragma unroll
    for (int m=0;m<8;m++)
      #pragma unroll
      for (int n=0;n<NRB;n++) acc[m][n] = f32x4{0.f,0.f,0.f,0.f};

    const unsigned short* pA[4]; const unsigned short* pB[NRB];
    int dA[4], dB[NRB];
    #pragma unroll
    for (int i=0;i<4;i++){
      int e = (i*512+tid)*8; int row = e>>6, col = e&63;
      int gr = mt*256 + row; if (gr > M-1) gr = M-1;
      pA[i] = A + (size_t)gr*K + col;
      dA[i] = swz(row,col);
    }
    #pragma unroll
    for (int i=0;i<NRB;i++){
      int e = (i*512+tid)*8; int row = e>>6, col = e&63;
      pB[i] = Bt + (size_t)(nt*BN+row)*K + col;
      dB[i] = swz(row,col);
    }

    u16x8 rA[4], rB[NRB];
    auto issue = [&](int k0){
      #pragma unroll
      for (int i=0;i<4;i++) rA[i] = *reinterpret_cast<const u16x8*>(pA[i]+k0);
      #pragma unroll
      for (int i=0;i<NRB;i++) rB[i] = *reinterpret_cast<const u16x8*>(pB[i]+k0);
    };
    auto commit = [&](){
      #pragma unroll
      for (int i=0;i<4;i++) *reinterpret_cast<u16x8*>(&As[dA[i]]) = rA[i];
      #pragma unroll
      for (int i=0;i<NRB;i++) *reinterpret_cast<u16x8*>(&Bs[dB[i]]) = rB[i];
    };

    issue(0);
    const int nk = K / 64;
    #pragma unroll 1
    for (int kt=0; kt<nk; kt++){
      __syncthreads();
      commit();
      __syncthreads();
      if (kt+1 < nk) issue((kt+1)*64);
      __builtin_amdgcn_sched_barrier(0);
      #pragma unroll
      for (int kk=0; kk<2; kk++){
        bf16x8 bv[NRB];
        #pragma unroll
        for (int n=0;n<NRB;n++){
          int r = wc*(NRB*16) + n*16 + (lane&15);
          bv[n] = (bf16x8)(*reinterpret_cast<const u16x8*>(&Bs[swz(r, kk*32 + (lane>>4)*8)]));
        }
        #pragma unroll
        for (int m=0;m<8;m++){
          int r = wr*128 + m*16 + (lane&15);
          bf16x8 av = (bf16x8)(*reinterpret_cast<const u16x8*>(&As[swz(r, kk*32 + (lane>>4)*8)]));
          #pragma unroll
          for (int n=0;n<NRB;n++)
            acc[m][n] = __builtin_amdgcn_mfma_f32_16x16x32_bf16(av, bv[n], acc[m][n], 0, 0, 0);
        }
      }
    }

    #pragma unroll
    for (int m=0;m<8;m++){
      #pragma unroll
      for (int n=0;n<NRB;n++){
        #pragma unroll
        for (int r=0;r<4;r++){
          int row = mt*256 + wr*128 + m*16 + (lane>>4)*4 + r;
          int col = nt*BN + wc*(NRB*16) + n*16 + (lane&15);
          if (row < M){
            float v = acc[m][n][r];
            if (bias) v += bias[col];
            Out[(size_t)row*N + col] = f2b(v);
          }
        }
      }
    }
}

// ---------------------------------------------------------------- split (Ootomo) GEMM (R13)
template<int EPI>
__global__ __launch_bounds__(256)
void gemm_sp2(const unsigned short* __restrict__ AH, const unsigned short* __restrict__ AL,
              const unsigned short* __restrict__ BH, const unsigned short* __restrict__ BL,
              const float* __restrict__ bias, const float* __restrict__ Res,
              void* __restrict__ Out, unsigned short* __restrict__ OutL,
              int M, int N, int K, int NT)
{
    constexpr int MR=2, NR=2;
    __shared__ unsigned short As[2*64*64];
    __shared__ unsigned short Bs[2*64*64];
    const int tid  = threadIdx.x;
    const int lane = tid & 63;
    const int wave = tid >> 6;
    const int wr = wave >> 1, wc = wave & 1;
    const int chunk = gridDim.x >> 3;
    const int nb = (blockIdx.x & 7)*chunk + (blockIdx.x >> 3);
    const int nt = nb % NT, mt = nb / NT;

    f32x4 acc[MR][NR];
    #pragma unroll
    for (int m=0;m<MR;m++)
      #pragma unroll
      for (int n=0;n<NR;n++) acc[m][n] = f32x4{0.f,0.f,0.f,0.f};

    const unsigned short *pA[2], *pB[2];
    int dst[2];
    #pragma unroll
    for (int i=0;i<2;i++){
      int e = (i*256+tid)*8; int row = e>>6, col = e&63;
      pA[i] = AH + (size_t)(mt*64+row)*K + col;
      pB[i] = BH + (size_t)(nt*64+row)*K + col;
      dst[i] = swz(row,col);
    }
    const size_t dAL = (size_t)(AL - AH);
    const size_t dBL = (size_t)(BL - BH);

    u16x8 rAH0[2], rAL0[2], rBH0[2], rBL0[2];
    u16x8 rAH1[2], rAL1[2], rBH1[2], rBL1[2];
    auto issue0 = [&](int k0){
      #pragma unroll
      for (int i=0;i<2;i++){
        rAH0[i] = *reinterpret_cast<const u16x8*>(pA[i]+k0);
        rAL0[i] = *reinterpret_cast<const u16x8*>(pA[i]+dAL+k0);
        rBH0[i] = *reinterpret_cast<const u16x8*>(pB[i]+k0);
        rBL0[i] = *reinterpret_cast<const u16x8*>(pB[i]+dBL+k0);
      }
    };
    auto issue1 = [&](int k0){
      #pragma unroll
      for (int i=0;i<2;i++){
        rAH1[i] = *reinterpret_cast<const u16x8*>(pA[i]+k0);
        rAL1[i] = *reinterpret_cast<const u16x8*>(pA[i]+dAL+k0);
        rBH1[i] = *reinterpret_cast<const u16x8*>(pB[i]+k0);
        rBL1[i] = *reinterpret_cast<const u16x8*>(pB[i]+dBL+k0);
      }
    };
    auto commit0 = [&](){
      #pragma unroll
      for (int i=0;i<2;i++){
        *reinterpret_cast<u16x8*>(&As[dst[i]])      = rAH0[i];
        *reinterpret_cast<u16x8*>(&As[4096+dst[i]]) = rAL0[i];
        *reinterpret_cast<u16x8*>(&Bs[dst[i]])      = rBH0[i];
        *reinterpret_cast<u16x8*>(&Bs[4096+dst[i]]) = rBL0[i];
      }
    };
    auto commit1 = [&](){
      #pragma unroll
      for (int i=0;i<2;i++){
        *reinterpret_cast<u16x8*>(&As[dst[i]])      = rAH1[i];
        *reinterpret_cast<u16x8*>(&As[4096+dst[i]]) = rAL1[i];
        *reinterpret_cast<u16x8*>(&Bs[dst[i]])      = rBH1[i];
        *reinterpret_cast<u16x8*>(&Bs[4096+dst[i]]) = rBL1[i];
      }
    };
    auto compute = [&](){
      #pragma unroll
      for (int kk=0; kk<2; kk++){
        bf16x8 ah[MR], al[MR], bh[NR], bl[NR];
        #pragma unroll
        for (int m=0;m<MR;m++){
          int a = swz(wr*32 + m*16 + (lane&15), kk*32 + (lane>>4)*8);
          ah[m] = (bf16x8)(*reinterpret_cast<const u16x8*>(&As[a]));
          al[m] = (bf16x8)(*reinterpret_cast<const u16x8*>(&As[4096 + a]));
        }
        #pragma unroll
        for (int n=0;n<NR;n++){
          int a = swz(wc*32 + n*16 + (lane&15), kk*32 + (lane>>4)*8);
          bh[n] = (bf16x8)(*reinterpret_cast<const u16x8*>(&Bs[a]));
          bl[n] = (bf16x8)(*reinterpret_cast<const u16x8*>(&Bs[4096 + a]));
        }
        #pragma unroll
        for (int m=0;m<MR;m++)
          #pragma unroll
          for (int n=0;n<NR;n++){
            acc[m][n] = __builtin_amdgcn_mfma_f32_16x16x32_bf16(ah[m], bh[n], acc[m][n], 0, 0, 0);
            acc[m][n] = __builtin_amdgcn_mfma_f32_16x16x32_bf16(ah[m], bl[n], acc[m][n], 0, 0, 0);
            acc[m][n] = __builtin_amdgcn_mfma_f32_16x16x32_bf16(al[m], bh[n], acc[m][n], 0, 0, 0);
          }
      }
    };

    const int nk = K / 64;
    issue0(0); issue1(64);
    #pragma unroll 1
    for (int kt=0; kt<nk; kt+=2){
      __syncthreads();
      commit0();
      __syncthreads();
      if (kt+2 < nk) issue0((kt+2)*64);
      __builtin_amdgcn_sched_barrier(0);
      compute();
      __syncthreads();
      commit1();
      __syncthreads();
      if (kt+3 < nk) issue1((kt+3)*64);
      __builtin_amdgcn_sched_barrier(0);
      compute();
    }

    #pragma unroll
    for (int m=0;m<MR;m++){
      #pragma unroll
      for (int n=0;n<NR;n++){
        #pragma unroll
        for (int r=0;r<4;r++){
          int row = mt*64 + wr*32 + m*16 + (lane>>4)*4 + r;
          int col = nt*64 + wc*32 + n*16 + (lane&15);
          float v = acc[m][n][r];
          if (bias) v += bias[col];
          if constexpr (EPI==EPI_GELU){
            v = 0.5f*v*(1.0f + erff(v*0.70710678118654752f));
            unsigned short hi = f2b(v);
            ((unsigned short*)Out)[(size_t)row*N + col] = hi;
            OutL[(size_t)row*N + col] = f2b(v - b2f(hi));
          } else {
            if constexpr (EPI==EPI_RESF32) v += Res[(size_t)row*N + col];
            ((float*)Out)[(size_t)row*N + col] = v;
          }
        }
      }
    }
}

// ---------------------------------------------------------------- split-K Ootomo GEMM (R13)
__global__ __launch_bounds__(256)
void gemm_spk(const unsigned short* __restrict__ AH, const unsigned short* __restrict__ AL,
              const unsigned short* __restrict__ BH, const unsigned short* __restrict__ BL,
              float* __restrict__ PART, int M, int N, int Kstride, int Klen, int NT)
{
    constexpr int MR=2, NR=2;
    __shared__ unsigned short As[2*64*64];
    __shared__ unsigned short Bs[2*64*64];
    const int tid  = threadIdx.x;
    const int lane = tid & 63;
    const int wave = tid >> 6;
    const int wr = wave >> 1, wc = wave & 1;
    const int nblk = (M>>6)*(N>>6);
    const int kchunk = blockIdx.x / nblk;
    const int rem = blockIdx.x - kchunk*nblk;
    const int cpx = nblk >> 3;
    const int nb = (rem & 7)*cpx + (rem >> 3);
    const int nt = nb % NT, mt = nb / NT;
    const int kbase = kchunk*Klen;

    f32x4 acc[MR][NR];
    #pragma unroll
    for (int m=0;m<MR;m++)
      #pragma unroll
      for (int n=0;n<NR;n++) acc[m][n] = f32x4{0.f,0.f,0.f,0.f};

    const unsigned short *pA[2], *pB[2];
    int dst[2];
    #pragma unroll
    for (int i=0;i<2;i++){
      int e = (i*256+tid)*8; int row = e>>6, col = e&63;
      pA[i] = AH + (size_t)(mt*64+row)*Kstride + kbase + col;
      pB[i] = BH + (size_t)(nt*64+row)*Kstride + kbase + col;
      dst[i] = swz(row,col);
    }
    const size_t dAL = (size_t)(AL - AH);
    const size_t dBL = (size_t)(BL - BH);

    u16x8 rAH0[2], rAL0[2], rBH0[2], rBL0[2];
    u16x8 rAH1[2], rAL1[2], rBH1[2], rBL1[2];
    auto issue0 = [&](int k0){
      #pragma unroll
      for (int i=0;i<2;i++){
        rAH0[i] = *reinterpret_cast<const u16x8*>(pA[i]+k0);
        rAL0[i] = *reinterpret_cast<const u16x8*>(pA[i]+dAL+k0);
        rBH0[i] = *reinterpret_cast<const u16x8*>(pB[i]+k0);
        rBL0[i] = *reinterpret_cast<const u16x8*>(pB[i]+dBL+k0);
      }
    };
    auto issue1 = [&](int k0){
      #pragma unroll
      for (int i=0;i<2;i++){
        rAH1[i] = *reinterpret_cast<const u16x8*>(pA[i]+k0);
        rAL1[i] = *reinterpret_cast<const u16x8*>(pA[i]+dAL+k0);
        rBH1[i] = *reinterpret_cast<const u16x8*>(pB[i]+k0);
        rBL1[i] = *reinterpret_cast<const u16x8*>(pB[i]+dBL+k0);
      }
    };
    auto commit0 = [&](){
      #pragma unroll
      for (int i=0;i<2;i++){
        *reinterpret_cast<u16x8*>(&As[dst[i]])      = rAH0[i];
        *reinterpret_cast<u16x8*>(&As[4096+dst[i]]) = rAL0[i];
        *reinterpret_cast<u16x8*>(&Bs[dst[i]])      = rBH0[i];
        *reinterpret_cast<u16x8*>(&Bs[4096+dst[i]]) = rBL0[i];
      }
    };
    auto commit1 = [&](){
      #pragma unroll
      for (int i=0;i<2;i++){
        *reinterpret_cast<u16x8*>(&As[dst[i]])      = rAH1[i];
        *reinterpret_cast<u16x8*>(&As[4096+dst[i]]) = rAL1[i];
        *reinterpret_cast<u16x8*>(&Bs[dst[i]])      = rBH1[i];
        *reinterpret_cast<u16x8*>(&Bs[4096+dst[i]]) = rBL1[i];
      }
    };
    auto compute = [&](){
      #pragma unroll
      for (int kk=0; kk<2; kk++){
        bf16x8 ah[MR], al[MR], bh[NR], bl[NR];
        #pragma unroll
        for (int m=0;m<MR;m++){
          int a = swz(wr*32 + m*16 + (lane&15), kk*32 + (lane>>4)*8);
          ah[m] = (bf16x8)(*reinterpret_cast<const u16x8*>(&As[a]));
          al[m] = (bf16x8)(*reinterpret_cast<const u16x8*>(&As[4096 + a]));
        }
        #pragma unroll
        for (int n=0;n<NR;n++){
          int a = swz(wc*32 + n*16 + (lane&15), kk*32 + (lane>>4)*8);
          bh[n] = (bf16x8)(*reinterpret_cast<const u16x8*>(&Bs[a]));
          bl[n] = (bf16x8)(*reinterpret_cast<const u16x8*>(&Bs[4096 + a]));
        }
        #pragma unroll
        for (int m=0;m<MR;m++)
          #pragma unroll
          for (int n=0;n<NR;n++){
            acc[m][n] = __builtin_amdgcn_mfma_f32_16x16x32_bf16(ah[m], bh[n], acc[m][n], 0, 0, 0);
            acc[m][n] = __builtin_amdgcn_mfma_f32_16x16x32_bf16(ah[m], bl[n], acc[m][n], 0, 0, 0);
            acc[m][n] = __builtin_amdgcn_mfma_f32_16x16x32_bf16(al[m], bh[n], acc[m][n], 0, 0, 0);
          }
      }
    };

    const int nk = Klen / 64;
    issue0(0); issue1(64);
    #pragma unroll 1
    for (int kt=0; kt<nk; kt+=2){
      __syncthreads();
      commit0();
      __syncthreads();
      if (kt+2 < nk) issue0((kt+2)*64);
      __builtin_amdgcn_sched_barrier(0);
      compute();
      __syncthreads();
      commit1();
      __syncthreads();
      if (kt+3 < nk) issue1((kt+3)*64);
      __builtin_amdgcn_sched_barrier(0);
      compute();
    }

    float* out = PART + (size_t)kchunk*M*N;
    #pragma unroll
    for (int m=0;m<MR;m++){
      #pragma unroll
      for (int n=0;n<NR;n++){
        #pragma unroll
        for (int r=0;r<4;r++){
          int row = mt*64 + wr*32 + m*16 + (lane>>4)*4 + r;
          int col = nt*64 + wc*32 + n*16 + (lane&15);
          out[(size_t)row*N + col] = acc[m][n][r];
        }
      }
    }
}

__global__ __launch_bounds__(256)
void reduce4_res(const float* __restrict__ PART, float* __restrict__ LATF)
{
  size_t i = ((size_t)blockIdx.x*256 + threadIdx.x)*4;
  f32x4 a = *reinterpret_cast<const f32x4*>(PART + i);
  f32x4 b = *reinterpret_cast<const f32x4*>(PART + 1048576 + i);
  f32x4 c = *reinterpret_cast<const f32x4*>(PART + 2097152 + i);
  f32x4 d = *reinterpret_cast<const f32x4*>(PART + 3145728 + i);
  f32x4 r = *reinterpret_cast<f32x4*>(LATF + i);
  #pragma unroll
  for (int j=0;j<4;j++) r[j] += a[j]+b[j]+c[j]+d[j];
  *reinterpret_cast<f32x4*>(LATF + i) = r;
}

__global__ __launch_bounds__(256)
void reduce_ln(const float* __restrict__ PART, float* __restrict__ LATF,
               unsigned short* __restrict__ Oh, unsigned short* __restrict__ Ol,
               const float* __restrict__ g, const float* __restrict__ bb)
{
  const int row = blockIdx.x;
  const int tid = threadIdx.x;
  const size_t base = (size_t)row*1024 + tid*4;
  f32x4 a = *reinterpret_cast<const f32x4*>(PART + base);
  f32x4 b4 = *reinterpret_cast<const f32x4*>(PART + 1048576 + base);
  f32x4 c = *reinterpret_cast<const f32x4*>(PART + 2097152 + base);
  f32x4 d = *reinterpret_cast<const f32x4*>(PART + 3145728 + base);
  f32x4 r = *reinterpret_cast<f32x4*>(LATF + base);
  float v[4];
  #pragma unroll
  for (int j=0;j<4;j++) v[j] = r[j] + a[j]+b4[j]+c[j]+d[j];
  f32x4 w{v[0],v[1],v[2],v[3]};
  *reinterpret_cast<f32x4*>(LATF + base) = w;

  float s = v[0]+v[1]+v[2]+v[3];
  float q = v[0]*v[0]+v[1]*v[1]+v[2]*v[2]+v[3]*v[3];
  #pragma unroll
  for (int o=32;o>0;o>>=1){ s += __shfl_xor(s,o,64); q += __shfl_xor(q,o,64); }
  __shared__ float sm[8];
  const int wave = tid>>6, lane = tid&63;
  if (lane==0){ sm[wave] = s; sm[4+wave] = q; }
  __syncthreads();
  s = sm[0]+sm[1]+sm[2]+sm[3];
  q = sm[4]+sm[5]+sm[6]+sm[7];
  const float mean = s*(1.f/1024.f);
  const float rstd = rsqrtf(fmaxf(q*(1.f/1024.f) - mean*mean, 0.f) + 1e-5f);
  #pragma unroll
  for (int j=0;j<4;j++)
    v[j] = (v[j]-mean)*rstd*g[tid*4+j] + bb[tid*4+j];
  u16x4 h{f2b(v[0]),f2b(v[1]),f2b(v[2]),f2b(v[3])};
  u16x4 l{f2b(v[0]-b2f(h[0])),f2b(v[1]-b2f(h[1])),f2b(v[2]-b2f(h[2])),f2b(v[3]-b2f(h[3]))};
  *reinterpret_cast<u16x4*>(Oh + base) = h;
  *reinterpret_cast<u16x4*>(Ol + base) = l;
}

// ---------------------------------------------------------------- LayerNorm (rows of 1024)
enum { OM_F32=0, OM_BF16=1, OM_SPLIT=2 };
template<bool INF32, int OM, bool HASGB>
__global__ __launch_bounds__(256)
void ln_rows(const void* __restrict__ In, void* __restrict__ Out,
             unsigned short* __restrict__ OutL,
             const float* __restrict__ g, const float* __restrict__ bb)
{
  const int row = blockIdx.x;
  const int tid = threadIdx.x;
  const size_t base = (size_t)row*1024 + tid*4;
  float v[4];
  if constexpr (INF32){
    f32x4 t = *reinterpret_cast<const f32x4*>((const float*)In + base);
    v[0]=t[0]; v[1]=t[1]; v[2]=t[2]; v[3]=t[3];
  } else {
    u16x4 t = *reinterpret_cast<const u16x4*>((const unsigned short*)In + base);
    #pragma unroll
    for (int j=0;j<4;j++) v[j] = b2f(t[j]);
  }
  float s = v[0]+v[1]+v[2]+v[3];
  float q = v[0]*v[0]+v[1]*v[1]+v[2]*v[2]+v[3]*v[3];
  #pragma unroll
  for (int o=32;o>0;o>>=1){ s += __shfl_xor(s,o,64); q += __shfl_xor(q,o,64); }
  __shared__ float sm[8];
  const int wave = tid>>6, lane = tid&63;
  if (lane==0){ sm[wave] = s; sm[4+wave] = q; }
  __syncthreads();
  s = sm[0]+sm[1]+sm[2]+sm[3];
  q = sm[4]+sm[5]+sm[6]+sm[7];
  const float mean = s*(1.f/1024.f);
  const float rstd = rsqrtf(fmaxf(q*(1.f/1024.f) - mean*mean, 0.f) + 1e-5f);
  #pragma unroll
  for (int j=0;j<4;j++){
    float t2 = (v[j]-mean)*rstd;
    if constexpr (HASGB) t2 = t2*g[tid*4+j] + bb[tid*4+j];
    v[j] = t2;
  }
  if constexpr (OM==OM_F32){
    f32x4 t{v[0],v[1],v[2],v[3]};
    *reinterpret_cast<f32x4*>((float*)Out + base) = t;
  } else if constexpr (OM==OM_BF16){
    u16x4 t{f2b(v[0]),f2b(v[1]),f2b(v[2]),f2b(v[3])};
    *reinterpret_cast<u16x4*>((unsigned short*)Out + base) = t;
  } else {
    u16x4 h{f2b(v[0]),f2b(v[1]),f2b(v[2]),f2b(v[3])};
    u16x4 l{f2b(v[0]-b2f(h[0])),f2b(v[1]-b2f(h[1])),f2b(v[2]-b2f(h[2])),f2b(v[3]-b2f(h[3]))};
    *reinterpret_cast<u16x4*>((unsigned short*)Out + base) = h;
    *reinterpret_cast<u16x4*>(OutL + base) = l;
  }
}

// ---------------------------------------------------------------- weight transpose (layer-batched)
template<bool LO>
__global__ __launch_bounds__(256)
void transpose_cvt_b(const float* __restrict__ W, const float* __restrict__ rs,
                     unsigned short* __restrict__ Wt, unsigned short* __restrict__ Wtlo,
                     int K, int N, size_t wLS, size_t tLS, int dstRowOff)
{
  const int l = blockIdx.z;
  const float* Wl = W + (size_t)l*wLS;
  __shared__ float t[32][33];
  const int tx = threadIdx.x & 31, ty = threadIdx.x >> 5;
  const int n0 = blockIdx.x*32, k0 = blockIdx.y*32;
  #pragma unroll
  for (int j=0;j<4;j++){
    int r = ty + j*8;
    float w = Wl[(size_t)(k0+r)*N + n0 + tx];
    if (rs) w *= rs[l*1024 + k0+r];
    t[r][tx] = w;
  }
  __syncthreads();
  #pragma unroll
  for (int j=0;j<4;j++){
    int r = ty + j*8;
    float w = t[tx][r];
    unsigned short hi = f2b(w);
    size_t di = (size_t)l*tLS + (size_t)(dstRowOff + n0 + r)*K + k0 + tx;
    Wt[di] = hi;
    if constexpr (LO) Wtlo[di] = f2b(w - b2f(hi));
  }
}

__global__ __launch_bounds__(256)
void biaskv_kernel(const float* __restrict__ ln1b, const float* __restrict__ wkv,
                   float* __restrict__ out)
{
  const int l = blockIdx.y;
  const int n = blockIdx.x*256 + threadIdx.x;
  const float* b1 = ln1b + l*1024;
  const float* W  = wkv + (size_t)l*1024*2048;
  float s = 0.f;
  for (int k=0;k<1024;k++) s += b1[k]*W[(size_t)k*2048 + n];
  out[l*2048 + n] = s;
}

__global__ __launch_bounds__(256)
void init_latents(const float* __restrict__ Q, float* __restrict__ L)
{
  size_t idx = ((size_t)blockIdx.x*256 + threadIdx.x)*4;
  int row = (int)(idx >> 10);
  int col = (int)(idx & 1023);
  f32x4 t = *reinterpret_cast<const f32x4*>(Q + (size_t)(row & 15)*1024 + col);
  *reinterpret_cast<f32x4*>(L + idx) = t;
}

__global__ __launch_bounds__(256)
void cvt_f32_bf16(const float* __restrict__ In, unsigned short* __restrict__ Out, size_t n4)
{
  size_t i = (size_t)blockIdx.x*256 + threadIdx.x;
  if (i >= n4) return;
  f32x4 t = *reinterpret_cast<const f32x4*>(In + i*4);
  u16x4 u{f2b(t[0]),f2b(t[1]),f2b(t[2]),f2b(t[3])};
  *reinterpret_cast<u16x4*>(Out + i*4) = u;
}

__global__ __launch_bounds__(256)
void cvt_f32b_pair(const float* __restrict__ In, unsigned short* __restrict__ Oh,
                   unsigned short* __restrict__ Ol)
{
  size_t idx = ((size_t)blockIdx.x*256 + threadIdx.x)*4;
  f32x4 t = *reinterpret_cast<const f32x4*>(In + idx);
  u16x4 h{f2b(t[0]),f2b(t[1]),f2b(t[2]),f2b(t[3])};
  u16x4 l{f2b(t[0]-b2f(h[0])),f2b(t[1]-b2f(h[1])),f2b(t[2]-b2f(h[2])),f2b(t[3]-b2f(h[3]))};
  *reinterpret_cast<u16x4*>(Oh + idx) = h;
  *reinterpret_cast<u16x4*>(Ol + idx) = l;
}

// ---------------------------------------------------------------- attention (R13)
__global__ __launch_bounds__(256)
void attn_kernel(const float* __restrict__ QKVf,
                 const unsigned short* __restrict__ KVX,
                 unsigned short* __restrict__ ATTOh,
                 unsigned short* __restrict__ ATTOl)
{
  __shared__ float qs[16][64];
  __shared__ float ws[16][600];
  const int tid = threadIdx.x;
  const int bh = blockIdx.x;
  const int b = bh >> 4, h = bh & 15;

  {
    int idx = tid*4;
    int qi = idx >> 6, d = idx & 63;
    f32x4 t = *reinterpret_cast<const f32x4*>(QKVf + (size_t)(b*16+qi)*3072 + h*64 + d);
    #pragma unroll
    for (int j=0;j<4;j++) qs[qi][d+j] = 0.125f * t[j];
  }
  __syncthreads();

  {
    const int r0 = tid*2;
    const unsigned short* k0 = KVX + ((size_t)(b*577 + r0)*2048 + h*64);
    const unsigned short* k1 = k0 + 2048;
    float a0[16], a1[16];
    #pragma unroll
    for (int qi=0;qi<16;qi++){ a0[qi]=0.f; a1[qi]=0.f; }
    #pragma unroll 4
    for (int d4=0; d4<16; d4++){
      u16x4 ka = *reinterpret_cast<const u16x4*>(k0 + d4*4);
      u16x4 kb = *reinterpret_cast<const u16x4*>(k1 + d4*4);
      float ka0=b2f(ka[0]), ka1=b2f(ka[1]), ka2=b2f(ka[2]), ka3=b2f(ka[3]);
      float kb0=b2f(kb[0]), kb1=b2f(kb[1]), kb2=b2f(kb[2]), kb3=b2f(kb[3]);
      #pragma unroll
      for (int qi=0;qi<16;qi++){
        f32x4 q4 = *reinterpret_cast<const f32x4*>(&qs[qi][d4*4]);
        a0[qi] += q4[0]*ka0 + q4[1]*ka1 + q4[2]*ka2 + q4[3]*ka3;
        a1[qi] += q4[0]*kb0 + q4[1]*kb1 + q4[2]*kb2 + q4[3]*kb3;
      }
    }
    #pragma unroll
    for (int qi=0;qi<16;qi++){ ws[qi][r0] = a0[qi]; ws[qi][r0+1] = a1[qi]; }
  }
  for (int r = 512 + tid; r < 593; r += 256){
    float a[16];
    #pragma unroll
    for (int qi=0;qi<16;qi++) a[qi] = 0.f;
    if (r < 577){
      const unsigned short* krow = KVX + ((size_t)(b*577 + r)*2048 + h*64);
      #pragma unroll 4
      for (int d4=0; d4<16; d4++){
        u16x4 k4 = *reinterpret_cast<const u16x4*>(krow + d4*4);
        float kf0=b2f(k4[0]), kf1=b2f(k4[1]), kf2=b2f(k4[2]), kf3=b2f(k4[3]);
        #pragma unroll
        for (int qi=0;qi<16;qi++){
          f32x4 q4 = *reinterpret_cast<const f32x4*>(&qs[qi][d4*4]);
          a[qi] += q4[0]*kf0 + q4[1]*kf1 + q4[2]*kf2 + q4[3]*kf3;
        }
      }
    } else {
      const float* krow = QKVf + (size_t)(b*16 + (r-577))*3072 + 1024 + h*64;
      #pragma unroll 4
      for (int d4=0; d4<16; d4++){
        f32x4 k4 = *reinterpret_cast<const f32x4*>(krow + d4*4);
        #pragma unroll
        for (int qi=0;qi<16;qi++){
          f32x4 q4 = *reinterpret_cast<const f32x4*>(&qs[qi][d4*4]);
          a[qi] += q4[0]*k4[0] + q4[1]*k4[1] + q4[2]*k4[2] + q4[3]*k4[3];
        }
      }
    }
    #pragma unroll
    for (int qi=0;qi<16;qi++) ws[qi][r] = a[qi];
  }
  __syncthreads();

  const int wave = tid>>6, lane = tid&63;
  for (int qi = wave; qi < 16; qi += 4){
    float m = -1e30f;
    for (int r = lane; r < 593; r += 64) m = fmaxf(m, ws[qi][r]);
    #pragma unroll
    for (int o=32;o>0;o>>=1) m = fmaxf(m, __shfl_xor(m,o,64));
    float s = 0.f;
    for (int r = lane; r < 593; r += 64){ float e = expf(ws[qi][r]-m); ws[qi][r] = e; s += e; }
    #pragma unroll
    for (int o=32;o>0;o>>=1) s += __shfl_xor(s,o,64);
    float inv = 1.f/s;
    for (int r = lane; r < 593; r += 64) ws[qi][r] *= inv;
  }
  __syncthreads();

  const int d = tid & 63, qg = tid >> 6;
  float o0=0.f,o1=0.f,o2=0.f,o3=0.f;
  for (int rr=0; rr<576; rr+=4){
    f32x4 w0 = *reinterpret_cast<const f32x4*>(&ws[qg   ][rr]);
    f32x4 w1 = *reinterpret_cast<const f32x4*>(&ws[qg+4 ][rr]);
    f32x4 w2 = *reinterpret_cast<const f32x4*>(&ws[qg+8 ][rr]);
    f32x4 w3 = *reinterpret_cast<const f32x4*>(&ws[qg+12][rr]);
    #pragma unroll
    for (int j=0;j<4;j++){
      const unsigned short* vrow = KVX + ((size_t)(b*577 + rr + j)*2048 + 1024 + h*64);
      float v = b2f(vrow[d]);
      o0 += w0[j]*v; o1 += w1[j]*v; o2 += w2[j]*v; o3 += w3[j]*v;
    }
  }
  {
    float v = b2f(KVX[(size_t)(b*577 + 576)*2048 + 1024 + h*64 + d]);
    o0 += ws[qg][576]*v; o1 += ws[qg+4][576]*v; o2 += ws[qg+8][576]*v; o3 += ws[qg+12][576]*v;
  }
  for (int r=577; r<593; r++){
    float v = QKVf[(size_t)(b*16 + (r-577))*3072 + 2048 + h*64 + d];
    o0 += ws[qg][r]*v; o1 += ws[qg+4][r]*v; o2 += ws[qg+8][r]*v; o3 += ws[qg+12][r]*v;
  }
  float ov[4] = {o0,o1,o2,o3};
  #pragma unroll
  for (int j=0;j<4;j++){
    size_t idx = (size_t)(b*16+qg+4*j)*1024 + h*64 + d;
    unsigned short hi = f2b(ov[j]);
    ATTOh[idx] = hi;
    ATTOl[idx] = f2b(ov[j] - b2f(hi));
  }
}

// ---------------------------------------------------------------- host
extern "C" void kernel_launch(void* const* d_in, const int* in_sizes, int n_in,
                              void* d_out, int out_size, void* d_ws, size_t ws_size,
                              hipStream_t stream)
{
  const float* x    = (const float*)d_in[0];
  const float* qry  = (const float*)d_in[1];
  const float* piw  = (const float*)d_in[2];
  const float* pib  = (const float*)d_in[3];
  const float* ln1g = (const float*)d_in[4];
  const float* ln1b = (const float*)d_in[5];
  const float* ln2g = (const float*)d_in[6];
  const float* ln2b = (const float*)d_in[7];
  const float* wq   = (const float*)d_in[8];
  const float* wkv  = (const float*)d_in[9];
  const float* wo   = (const float*)d_in[10];
  const float* ffg  = (const float*)d_in[11];
  const float* ffb  = (const float*)d_in[12];
  const float* w1   = (const float*)d_in[13];
  const float* w2   = (const float*)d_in[14];
  const float* pow_ = (const float*)d_in[15];
  const float* pob  = (const float*)d_in[16];
  const float* ng   = (const float*)d_in[17];
  const float* nb   = (const float*)d_in[18];

  const int MROWS = 64*577;     // 36928; 145 tiles of 256
  char* wsb = (char*)d_ws;
  size_t off = 0;
  auto alloc = [&](size_t bytes)->char*{
    char* p = wsb + off; off = (off + bytes + 255) & ~(size_t)255; return p;
  };
  unsigned short* XB     = (unsigned short*)alloc((size_t)36992*768*2);  // also PART later
  unsigned short* XP     = (unsigned short*)alloc((size_t)36992*1024*2);
  unsigned short* KVX    = (unsigned short*)alloc((size_t)36992*2048*2);
  unsigned short* WpiT   = (unsigned short*)alloc((size_t)1024*768*2);
  unsigned short* WkvTs  = (unsigned short*)alloc((size_t)8*2048*1024*2);
  unsigned short* WqkvT  = (unsigned short*)alloc((size_t)8*3072*1024*2);
  unsigned short* WqkvTl = (unsigned short*)alloc((size_t)8*3072*1024*2);
  unsigned short* WoT    = (unsigned short*)alloc((size_t)8*1024*1024*2);
  unsigned short* WoTl   = (unsigned short*)alloc((size_t)8*1024*1024*2);
  unsigned short* W1T    = (unsigned short*)alloc((size_t)4096*1024*2);
  unsigned short* W1Tl   = (unsigned short*)alloc((size_t)4096*1024*2);
  unsigned short* W2T    = (unsigned short*)alloc((size_t)1024*4096*2);
  unsigned short* W2Tl   = (unsigned short*)alloc((size_t)1024*4096*2);
  float*          BKV    = (float*)alloc((size_t)8*2048*4);
  unsigned short* LTh    = (unsigned short*)alloc((size_t)1024*1024*2);
  unsigned short* LTl    = (unsigned short*)alloc((size_t)1024*1024*2);
  float*          QKVf   = (float*)alloc((size_t)1024*3072*4);
  unsigned short* ATTOh  = (unsigned short*)alloc((size_t)1024*1024*2);
  unsigned short* ATTOl  = (unsigned short*)alloc((size_t)1024*1024*2);
  unsigned short* FFHh   = (unsigned short*)alloc((size_t)1024*4096*2);
  unsigned short* FFHl   = (unsigned short*)alloc((size_t)1024*4096*2);
  unsigned short* LATBh  = (unsigned short*)alloc((size_t)1024*1024*2);
  unsigned short* LATBl  = (unsigned short*)alloc((size_t)1024*1024*2);
  float*          LATF   = (float*)alloc((size_t)1024*1024*4);
  if (off > ws_size) return;  // loud failure
  float* PART = (float*)XB;

  dim3 blk(256);
  dim3 blk5(512);

  // ---- prep
  cvt_f32_bf16<<<dim3((36928*768/4 + 255)/256), blk, 0, stream>>>(x, XB, (size_t)36928*768/4);
  transpose_cvt_b<false><<<dim3(32,24,1), blk, 0, stream>>>(piw, nullptr, WpiT, nullptr, 768, 1024, 0, 0, 0);
  transpose_cvt_b<false><<<dim3(64,32,8), blk, 0, stream>>>(wkv, ln1g, WkvTs, nullptr, 1024, 2048, (size_t)1024*2048, (size_t)2048*1024, 0);
  transpose_cvt_b<true ><<<dim3(32,32,8), blk, 0, stream>>>(wq,  nullptr, WqkvT, WqkvTl, 1024, 1024, (size_t)1024*1024, (size_t)3072*1024, 0);
  transpose_cvt_b<true ><<<dim3(64,32,8), blk, 0, stream>>>(wkv, nullptr, WqkvT, WqkvTl, 1024, 2048, (size_t)1024*2048, (size_t)3072*1024, 1024);
  transpose_cvt_b<true ><<<dim3(32,32,8), blk, 0, stream>>>(wo,  nullptr, WoT, WoTl, 1024, 1024, (size_t)1024*1024, (size_t)1024*1024, 0);
  biaskv_kernel<<<dim3(8,8), blk, 0, stream>>>(ln1b, wkv, BKV);
  init_latents<<<dim3(1024), blk, 0, stream>>>(qry, LATF);

  // xp = x @ proj_in_w + b, then LN in place -> xhat (bf16); BN=128 -> NT=8
  gemm3<2><<<dim3(145*8), blk5, 0, stream>>>(XB, WpiT, pib, XP, MROWS, 1024, 768, 8);
  ln_rows<false,OM_BF16,false><<<dim3(MROWS), blk, 0, stream>>>(XP, XP, nullptr, nullptr, nullptr);

  // lt for layer 0
  ln_rows<true,OM_SPLIT,true><<<dim3(1024), blk, 0, stream>>>(LATF, LTh, LTl, ln2g, ln2b);

  for (int l=0; l<8; l++){
    transpose_cvt_b<true><<<dim3(128,32,1), blk, 0, stream>>>(w1 + (size_t)l*1024*4096, nullptr, W1T, W1Tl, 1024, 4096, 0, 0, 0);
    transpose_cvt_b<true><<<dim3(32,128,1), blk, 0, stream>>>(w2 + (size_t)l*4096*1024, nullptr, W2T, W2Tl, 4096, 1024, 0, 0, 0);

    // qkv_lt = lt @ [Wq|Wkv]  (split, fp32-accurate)
    gemm_sp2<EPI_F32><<<dim3(16*48), blk, 0, stream>>>(
        LTh, LTl, WqkvT + (size_t)l*3072*1024, WqkvTl + (size_t)l*3072*1024,
        nullptr, nullptr, QKVf, nullptr, 1024, 3072, 1024, 48);
    // kv_x = xhat @ (g1-scaled Wkv) + b1@Wkv   (BN=128 -> NT=16, 3 blocks/CU)
    gemm3<2><<<dim3(145*16), blk5, 0, stream>>>(
        XP, WkvTs + (size_t)l*2048*1024, BKV + l*2048, KVX, MROWS, 2048, 1024, 16);
    // attention
    attn_kernel<<<dim3(1024), blk, 0, stream>>>(QKVf, KVX, ATTOh, ATTOl);
    // latents += o @ Wo  (split)
    gemm_sp2<EPI_RESF32><<<dim3(16*16), blk, 0, stream>>>(
        ATTOh, ATTOl, WoT + (size_t)l*1024*1024, WoTl + (size_t)l*1024*1024,
        nullptr, LATF, LATF, nullptr, 1024, 1024, 1024, 16);
    // FF (split)
    ln_rows<true,OM_SPLIT,true><<<dim3(1024), blk, 0, stream>>>(LATF, LTh, LTl, ffg + l*1024, ffb + l*1024);
    gemm_sp2<EPI_GELU><<<dim3(16*64), blk, 0, stream>>>(
        LTh, LTl, W1T, W1Tl, nullptr, nullptr, FFHh, FFHl, 1024, 4096, 1024, 64);
    gemm_spk<<<dim3(4*16*16), blk, 0, stream>>>(
        FFHh, FFHl, W2T, W2Tl, PART, 1024, 1024, 4096, 1024, 16);
    if (l < 7){
      reduce_ln<<<dim3(1024), blk, 0, stream>>>(PART, LATF, LTh, LTl, ln2g + (l+1)*1024, ln2b + (l+1)*1024);
    } else {
      reduce4_res<<<dim3(1024), blk, 0, stream>>>(PART, LATF);
    }
  }

  // out = LN(latents @ Wpo + b, nout)
  transpose_cvt_b<true><<<dim3(32,32,1), blk, 0, stream>>>(pow_, nullptr, W1T, W1Tl, 1024, 1024, 0, 0, 0);
  cvt_f32b_pair<<<dim3(1024), blk, 0, stream>>>(LATF, LATBh, LATBl);
  gemm_sp2<EPI_F32><<<dim3(16*16), blk, 0, stream>>>(
      LATBh, LATBl, W1T, W1Tl, pob, nullptr, QKVf, nullptr, 1024, 1024, 1024, 16);
  ln_rows<true,OM_F32,true><<<dim3(1024), blk, 0, stream>>>(QKVf, d_out, nullptr, ng, nb);
}

// Round 17
// 4942.385 us; speedup vs baseline: 1.0872x; 1.0872x over previous
//
#include <hip/hip_runtime.h>
#include <hip/hip_bf16.h>
#include <math.h>

#define DEV __device__ __forceinline__

typedef __bf16 bf16x8 __attribute__((ext_vector_type(8)));
typedef float f32x4 __attribute__((ext_vector_type(4)));
typedef unsigned short u16x8 __attribute__((ext_vector_type(8)));
typedef unsigned short u16x4 __attribute__((ext_vector_type(4)));

DEV float b2f(unsigned short u){ unsigned int i = ((unsigned int)u)<<16; float f; __builtin_memcpy(&f,&i,4); return f; }
DEV unsigned short f2b(float x){ unsigned int i; __builtin_memcpy(&i,&x,4); unsigned int r = i + 0x7FFFu + ((i>>16)&1u); return (unsigned short)(r>>16); }

// XOR-swizzled element index within a [rows][64] u16 plane (16B-unit swizzle).
DEV int swz(int row, int elem){ return row*64 + ((((elem>>3) ^ row) & 7)<<3) + (elem&7); }

// bijective XCD-chunk swizzle (m204)
DEV int xcd_swz(int orig, int nwg){
  int q = nwg >> 3, r = nwg & 7;
  int x = orig & 7, idx = orig >> 3;
  return (x < r ? x*(q+1) : r*(q+1) + (x-r)*q) + idx;
}

enum { EPI_F32=0, EPI_GELU=2, EPI_RESF32=3 };

// ---------------------------------------------------------------- 256^2 bf16 GEMM, reg-staged (best: R13)
__global__ __launch_bounds__(512)
void gemm3(const unsigned short* __restrict__ A, const unsigned short* __restrict__ Bt,
           const float* __restrict__ bias, unsigned short* __restrict__ Out,
           int M, int N, int K, int NT)
{
    __shared__ unsigned short As[256*64];
    __shared__ unsigned short Bs[256*64];
    const int tid  = threadIdx.x;
    const int lane = tid & 63;
    const int wave = tid >> 6;
    const int wr = wave >> 2, wc = wave & 3;
    const int nb = xcd_swz(blockIdx.x, gridDim.x);
    const int nt = nb % NT, mt = nb / NT;

    f32x4 acc[8][4];
    #pragma unroll
    for (int m=0;m<8;m++)
      #pragma unroll
      for (int n=0;n<4;n++) acc[m][n] = f32x4{0.f,0.f,0.f,0.f};

    const unsigned short* pA[4]; const unsigned short* pB[4];
    int dA[4], dB[4];
    #pragma unroll
    for (int i=0;i<4;i++){
      int e = (i*512+tid)*8; int row = e>>6, col = e&63;
      int gr = mt*256 + row; if (gr > M-1) gr = M-1;
      pA[i] = A + (size_t)gr*K + col;
      dA[i] = swz(row,col);
      pB[i] = Bt + (size_t)(nt*256+row)*K + col;
      dB[i] = swz(row,col);
    }

    u16x8 rA[4], rB[4];
    auto issue = [&](int k0){
      #pragma unroll
      for (int i=0;i<4;i++) rA[i] = *reinterpret_cast<const u16x8*>(pA[i]+k0);
      #pragma unroll
      for (int i=0;i<4;i++) rB[i] = *reinterpret_cast<const u16x8*>(pB[i]+k0);
    };
    auto commit = [&](){
      #pragma unroll
      for (int i=0;i<4;i++) *reinterpret_cast<u16x8*>(&As[dA[i]]) = rA[i];
      #pragma unroll
      for (int i=0;i<4;i++) *reinterpret_cast<u16x8*>(&Bs[dB[i]]) = rB[i];
    };

    issue(0);
    const int nk = K / 64;
    #pragma unroll 1
    for (int kt=0; kt<nk; kt++){
      __syncthreads();
      commit();
      __syncthreads();
      if (kt+1 < nk) issue((kt+1)*64);
      __builtin_amdgcn_sched_barrier(0);
      #pragma unroll
      for (int kk=0; kk<2; kk++){
        bf16x8 bv[4];
        #pragma unroll
        for (int n=0;n<4;n++){
          int r = wc*64 + n*16 + (lane&15);
          bv[n] = (bf16x8)(*reinterpret_cast<const u16x8*>(&Bs[swz(r, kk*32 + (lane>>4)*8)]));
        }
        #pragma unroll
        for (int m=0;m<8;m++){
          int r = wr*128 + m*16 + (lane&15);
          bf16x8 av = (bf16x8)(*reinterpret_cast<const u16x8*>(&As[swz(r, kk*32 + (lane>>4)*8)]));
          #pragma unroll
          for (int n=0;n<4;n++)
            acc[m][n] = __builtin_amdgcn_mfma_f32_16x16x32_bf16(av, bv[n], acc[m][n], 0, 0, 0);
        }
      }
    }

    #pragma unroll
    for (int m=0;m<8;m++){
      #pragma unroll
      for (int n=0;n<4;n++){
        #pragma unroll
        for (int r=0;r<4;r++){
          int row = mt*256 + wr*128 + m*16 + (lane>>4)*4 + r;
          int col = nt*256 + wc*64 + n*16 + (lane&15);
          if (row < M){
            float v = acc[m][n][r];
            if (bias) v += bias[col];
            Out[(size_t)row*N + col] = f2b(v);
          }
        }
      }
    }
}

// ---------------------------------------------------------------- split (Ootomo) GEMM (R13)
template<int EPI>
__global__ __launch_bounds__(256)
void gemm_sp2(const unsigned short* __restrict__ AH, const unsigned short* __restrict__ AL,
              const unsigned short* __restrict__ BH, const unsigned short* __restrict__ BL,
              const float* __restrict__ bias, const float* __restrict__ Res,
              void* __restrict__ Out, unsigned short* __restrict__ OutL,
              int M, int N, int K, int NT)
{
    constexpr int MR=2, NR=2;
    __shared__ unsigned short As[2*64*64];
    __shared__ unsigned short Bs[2*64*64];
    const int tid  = threadIdx.x;
    const int lane = tid & 63;
    const int wave = tid >> 6;
    const int wr = wave >> 1, wc = wave & 1;
    const int chunk = gridDim.x >> 3;
    const int nb = (blockIdx.x & 7)*chunk + (blockIdx.x >> 3);
    const int nt = nb % NT, mt = nb / NT;

    f32x4 acc[MR][NR];
    #pragma unroll
    for (int m=0;m<MR;m++)
      #pragma unroll
      for (int n=0;n<NR;n++) acc[m][n] = f32x4{0.f,0.f,0.f,0.f};

    const unsigned short *pA[2], *pB[2];
    int dst[2];
    #pragma unroll
    for (int i=0;i<2;i++){
      int e = (i*256+tid)*8; int row = e>>6, col = e&63;
      pA[i] = AH + (size_t)(mt*64+row)*K + col;
      pB[i] = BH + (size_t)(nt*64+row)*K + col;
      dst[i] = swz(row,col);
    }
    const size_t dAL = (size_t)(AL - AH);
    const size_t dBL = (size_t)(BL - BH);

    u16x8 rAH0[2], rAL0[2], rBH0[2], rBL0[2];
    u16x8 rAH1[2], rAL1[2], rBH1[2], rBL1[2];
    auto issue0 = [&](int k0){
      #pragma unroll
      for (int i=0;i<2;i++){
        rAH0[i] = *reinterpret_cast<const u16x8*>(pA[i]+k0);
        rAL0[i] = *reinterpret_cast<const u16x8*>(pA[i]+dAL+k0);
        rBH0[i] = *reinterpret_cast<const u16x8*>(pB[i]+k0);
        rBL0[i] = *reinterpret_cast<const u16x8*>(pB[i]+dBL+k0);
      }
    };
    auto issue1 = [&](int k0){
      #pragma unroll
      for (int i=0;i<2;i++){
        rAH1[i] = *reinterpret_cast<const u16x8*>(pA[i]+k0);
        rAL1[i] = *reinterpret_cast<const u16x8*>(pA[i]+dAL+k0);
        rBH1[i] = *reinterpret_cast<const u16x8*>(pB[i]+k0);
        rBL1[i] = *reinterpret_cast<const u16x8*>(pB[i]+dBL+k0);
      }
    };
    auto commit0 = [&](){
      #pragma unroll
      for (int i=0;i<2;i++){
        *reinterpret_cast<u16x8*>(&As[dst[i]])      = rAH0[i];
        *reinterpret_cast<u16x8*>(&As[4096+dst[i]]) = rAL0[i];
        *reinterpret_cast<u16x8*>(&Bs[dst[i]])      = rBH0[i];
        *reinterpret_cast<u16x8*>(&Bs[4096+dst[i]]) = rBL0[i];
      }
    };
    auto commit1 = [&](){
      #pragma unroll
      for (int i=0;i<2;i++){
        *reinterpret_cast<u16x8*>(&As[dst[i]])      = rAH1[i];
        *reinterpret_cast<u16x8*>(&As[4096+dst[i]]) = rAL1[i];
        *reinterpret_cast<u16x8*>(&Bs[dst[i]])      = rBH1[i];
        *reinterpret_cast<u16x8*>(&Bs[4096+dst[i]]) = rBL1[i];
      }
    };
    auto compute = [&](){
      #pragma unroll
      for (int kk=0; kk<2; kk++){
        bf16x8 ah[MR], al[MR], bh[NR], bl[NR];
        #pragma unroll
        for (int m=0;m<MR;m++){
          int a = swz(wr*32 + m*16 + (lane&15), kk*32 + (lane>>4)*8);
          ah[m] = (bf16x8)(*reinterpret_cast<const u16x8*>(&As[a]));
          al[m] = (bf16x8)(*reinterpret_cast<const u16x8*>(&As[4096 + a]));
        }
        #pragma unroll
        for (int n=0;n<NR;n++){
          int a = swz(wc*32 + n*16 + (lane&15), kk*32 + (lane>>4)*8);
          bh[n] = (bf16x8)(*reinterpret_cast<const u16x8*>(&Bs[a]));
          bl[n] = (bf16x8)(*reinterpret_cast<const u16x8*>(&Bs[4096 + a]));
        }
        #pragma unroll
        for (int m=0;m<MR;m++)
          #pragma unroll
          for (int n=0;n<NR;n++){
            acc[m][n] = __builtin_amdgcn_mfma_f32_16x16x32_bf16(ah[m], bh[n], acc[m][n], 0, 0, 0);
            acc[m][n] = __builtin_amdgcn_mfma_f32_16x16x32_bf16(ah[m], bl[n], acc[m][n], 0, 0, 0);
            acc[m][n] = __builtin_amdgcn_mfma_f32_16x16x32_bf16(al[m], bh[n], acc[m][n], 0, 0, 0);
          }
      }
    };

    const int nk = K / 64;
    issue0(0); issue1(64);
    #pragma unroll 1
    for (int kt=0; kt<nk; kt+=2){
      __syncthreads();
      commit0();
      __syncthreads();
      if (kt+2 < nk) issue0((kt+2)*64);
      __builtin_amdgcn_sched_barrier(0);
      compute();
      __syncthreads();
      commit1();
      __syncthreads();
      if (kt+3 < nk) issue1((kt+3)*64);
      __builtin_amdgcn_sched_barrier(0);
      compute();
    }

    #pragma unroll
    for (int m=0;m<MR;m++){
      #pragma unroll
      for (int n=0;n<NR;n++){
        #pragma unroll
        for (int r=0;r<4;r++){
          int row = mt*64 + wr*32 + m*16 + (lane>>4)*4 + r;
          int col = nt*64 + wc*32 + n*16 + (lane&15);
          float v = acc[m][n][r];
          if (bias) v += bias[col];
          if constexpr (EPI==EPI_GELU){
            v = 0.5f*v*(1.0f + erff(v*0.70710678118654752f));
            unsigned short hi = f2b(v);
            ((unsigned short*)Out)[(size_t)row*N + col] = hi;
            OutL[(size_t)row*N + col] = f2b(v - b2f(hi));
          } else {
            if constexpr (EPI==EPI_RESF32) v += Res[(size_t)row*N + col];
            ((float*)Out)[(size_t)row*N + col] = v;
          }
        }
      }
    }
}

// ---------------------------------------------------------------- split-K Ootomo GEMM (R13)
__global__ __launch_bounds__(256)
void gemm_spk(const unsigned short* __restrict__ AH, const unsigned short* __restrict__ AL,
              const unsigned short* __restrict__ BH, const unsigned short* __restrict__ BL,
              float* __restrict__ PART, int M, int N, int Kstride, int Klen, int NT)
{
    constexpr int MR=2, NR=2;
    __shared__ unsigned short As[2*64*64];
    __shared__ unsigned short Bs[2*64*64];
    const int tid  = threadIdx.x;
    const int lane = tid & 63;
    const int wave = tid >> 6;
    const int wr = wave >> 1, wc = wave & 1;
    const int nblk = (M>>6)*(N>>6);
    const int kchunk = blockIdx.x / nblk;
    const int rem = blockIdx.x - kchunk*nblk;
    const int cpx = nblk >> 3;
    const int nb = (rem & 7)*cpx + (rem >> 3);
    const int nt = nb % NT, mt = nb / NT;
    const int kbase = kchunk*Klen;

    f32x4 acc[MR][NR];
    #pragma unroll
    for (int m=0;m<MR;m++)
      #pragma unroll
      for (int n=0;n<NR;n++) acc[m][n] = f32x4{0.f,0.f,0.f,0.f};

    const unsigned short *pA[2], *pB[2];
    int dst[2];
    #pragma unroll
    for (int i=0;i<2;i++){
      int e = (i*256+tid)*8; int row = e>>6, col = e&63;
      pA[i] = AH + (size_t)(mt*64+row)*Kstride + kbase + col;
      pB[i] = BH + (size_t)(nt*64+row)*Kstride + kbase + col;
      dst[i] = swz(row,col);
    }
    const size_t dAL = (size_t)(AL - AH);
    const size_t dBL = (size_t)(BL - BH);

    u16x8 rAH0[2], rAL0[2], rBH0[2], rBL0[2];
    u16x8 rAH1[2], rAL1[2], rBH1[2], rBL1[2];
    auto issue0 = [&](int k0){
      #pragma unroll
      for (int i=0;i<2;i++){
        rAH0[i] = *reinterpret_cast<const u16x8*>(pA[i]+k0);
        rAL0[i] = *reinterpret_cast<const u16x8*>(pA[i]+dAL+k0);
        rBH0[i] = *reinterpret_cast<const u16x8*>(pB[i]+k0);
        rBL0[i] = *reinterpret_cast<const u16x8*>(pB[i]+dBL+k0);
      }
    };
    auto issue1 = [&](int k0){
      #pragma unroll
      for (int i=0;i<2;i++){
        rAH1[i] = *reinterpret_cast<const u16x8*>(pA[i]+k0);
        rAL1[i] = *reinterpret_cast<const u16x8*>(pA[i]+dAL+k0);
        rBH1[i] = *reinterpret_cast<const u16x8*>(pB[i]+k0);
        rBL1[i] = *reinterpret_cast<const u16x8*>(pB[i]+dBL+k0);
      }
    };
    auto commit0 = [&](){
      #pragma unroll
      for (int i=0;i<2;i++){
        *reinterpret_cast<u16x8*>(&As[dst[i]])      = rAH0[i];
        *reinterpret_cast<u16x8*>(&As[4096+dst[i]]) = rAL0[i];
        *reinterpret_cast<u16x8*>(&Bs[dst[i]])      = rBH0[i];
        *reinterpret_cast<u16x8*>(&Bs[4096+dst[i]]) = rBL0[i];
      }
    };
    auto commit1 = [&](){
      #pragma unroll
      for (int i=0;i<2;i++){
        *reinterpret_cast<u16x8*>(&As[dst[i]])      = rAH1[i];
        *reinterpret_cast<u16x8*>(&As[4096+dst[i]]) = rAL1[i];
        *reinterpret_cast<u16x8*>(&Bs[dst[i]])      = rBH1[i];
        *reinterpret_cast<u16x8*>(&Bs[4096+dst[i]]) = rBL1[i];
      }
    };
    auto compute = [&](){
      #pragma unroll
      for (int kk=0; kk<2; kk++){
        bf16x8 ah[MR], al[MR], bh[NR], bl[NR];
        #pragma unroll
        for (int m=0;m<MR;m++){
          int a = swz(wr*32 + m*16 + (lane&15), kk*32 + (lane>>4)*8);
          ah[m] = (bf16x8)(*reinterpret_cast<const u16x8*>(&As[a]));
          al[m] = (bf16x8)(*reinterpret_cast<const u16x8*>(&As[4096 + a]));
        }
        #pragma unroll
        for (int n=0;n<NR;n++){
          int a = swz(wc*32 + n*16 + (lane&15), kk*32 + (lane>>4)*8);
          bh[n] = (bf16x8)(*reinterpret_cast<const u16x8*>(&Bs[a]));
          bl[n] = (bf16x8)(*reinterpret_cast<const u16x8*>(&Bs[4096 + a]));
        }
        #pragma unroll
        for (int m=0;m<MR;m++)
          #pragma unroll
          for (int n=0;n<NR;n++){
            acc[m][n] = __builtin_amdgcn_mfma_f32_16x16x32_bf16(ah[m], bh[n], acc[m][n], 0, 0, 0);
            acc[m][n] = __builtin_amdgcn_mfma_f32_16x16x32_bf16(ah[m], bl[n], acc[m][n], 0, 0, 0);
            acc[m][n] = __builtin_amdgcn_mfma_f32_16x16x32_bf16(al[m], bh[n], acc[m][n], 0, 0, 0);
          }
      }
    };

    const int nk = Klen / 64;
    issue0(0); issue1(64);
    #pragma unroll 1
    for (int kt=0; kt<nk; kt+=2){
      __syncthreads();
      commit0();
      __syncthreads();
      if (kt+2 < nk) issue0((kt+2)*64);
      __builtin_amdgcn_sched_barrier(0);
      compute();
      __syncthreads();
      commit1();
      __syncthreads();
      if (kt+3 < nk) issue1((kt+3)*64);
      __builtin_amdgcn_sched_barrier(0);
      compute();
    }

    float* out = PART + (size_t)kchunk*M*N;
    #pragma unroll
    for (int m=0;m<MR;m++){
      #pragma unroll
      for (int n=0;n<NR;n++){
        #pragma unroll
        for (int r=0;r<4;r++){
          int row = mt*64 + wr*32 + m*16 + (lane>>4)*4 + r;
          int col = nt*64 + wc*32 + n*16 + (lane&15);
          out[(size_t)row*N + col] = acc[m][n][r];
        }
      }
    }
}

__global__ __launch_bounds__(256)
void reduce4_res(const float* __restrict__ PART, float* __restrict__ LATF)
{
  size_t i = ((size_t)blockIdx.x*256 + threadIdx.x)*4;
  f32x4 a = *reinterpret_cast<const f32x4*>(PART + i);
  f32x4 b = *reinterpret_cast<const f32x4*>(PART + 1048576 + i);
  f32x4 c = *reinterpret_cast<const f32x4*>(PART + 2097152 + i);
  f32x4 d = *reinterpret_cast<const f32x4*>(PART + 3145728 + i);
  f32x4 r = *reinterpret_cast<f32x4*>(LATF + i);
  #pragma unroll
  for (int j=0;j<4;j++) r[j] += a[j]+b[j]+c[j]+d[j];
  *reinterpret_cast<f32x4*>(LATF + i) = r;
}

// fused: LATF += sum(PART x4); emit LN(LATF)*g+b as hi/lo planes (next layer's lt)
__global__ __launch_bounds__(256)
void reduce_ln(const float* __restrict__ PART, float* __restrict__ LATF,
               unsigned short* __restrict__ Oh, unsigned short* __restrict__ Ol,
               const float* __restrict__ g, const float* __restrict__ bb)
{
  const int row = blockIdx.x;
  const int tid = threadIdx.x;
  const size_t base = (size_t)row*1024 + tid*4;
  f32x4 a = *reinterpret_cast<const f32x4*>(PART + base);
  f32x4 b4 = *reinterpret_cast<const f32x4*>(PART + 1048576 + base);
  f32x4 c = *reinterpret_cast<const f32x4*>(PART + 2097152 + base);
  f32x4 d = *reinterpret_cast<const f32x4*>(PART + 3145728 + base);
  f32x4 r = *reinterpret_cast<f32x4*>(LATF + base);
  float v[4];
  #pragma unroll
  for (int j=0;j<4;j++) v[j] = r[j] + a[j]+b4[j]+c[j]+d[j];
  f32x4 w{v[0],v[1],v[2],v[3]};
  *reinterpret_cast<f32x4*>(LATF + base) = w;

  float s = v[0]+v[1]+v[2]+v[3];
  float q = v[0]*v[0]+v[1]*v[1]+v[2]*v[2]+v[3]*v[3];
  #pragma unroll
  for (int o=32;o>0;o>>=1){ s += __shfl_xor(s,o,64); q += __shfl_xor(q,o,64); }
  __shared__ float sm[8];
  const int wave = tid>>6, lane = tid&63;
  if (lane==0){ sm[wave] = s; sm[4+wave] = q; }
  __syncthreads();
  s = sm[0]+sm[1]+sm[2]+sm[3];
  q = sm[4]+sm[5]+sm[6]+sm[7];
  const float mean = s*(1.f/1024.f);
  const float rstd = rsqrtf(fmaxf(q*(1.f/1024.f) - mean*mean, 0.f) + 1e-5f);
  #pragma unroll
  for (int j=0;j<4;j++)
    v[j] = (v[j]-mean)*rstd*g[tid*4+j] + bb[tid*4+j];
  u16x4 h{f2b(v[0]),f2b(v[1]),f2b(v[2]),f2b(v[3])};
  u16x4 l{f2b(v[0]-b2f(h[0])),f2b(v[1]-b2f(h[1])),f2b(v[2]-b2f(h[2])),f2b(v[3]-b2f(h[3]))};
  *reinterpret_cast<u16x4*>(Oh + base) = h;
  *reinterpret_cast<u16x4*>(Ol + base) = l;
}

// ---------------------------------------------------------------- LayerNorm (rows of 1024)
enum { OM_F32=0, OM_BF16=1, OM_SPLIT=2 };
template<bool INF32, int OM, bool HASGB>
__global__ __launch_bounds__(256)
void ln_rows(const void* __restrict__ In, void* __restrict__ Out,
             unsigned short* __restrict__ OutL,
             const float* __restrict__ g, const float* __restrict__ bb)
{
  const int row = blockIdx.x;
  const int tid = threadIdx.x;
  const size_t base = (size_t)row*1024 + tid*4;
  float v[4];
  if constexpr (INF32){
    f32x4 t = *reinterpret_cast<const f32x4*>((const float*)In + base);
    v[0]=t[0]; v[1]=t[1]; v[2]=t[2]; v[3]=t[3];
  } else {
    u16x4 t = *reinterpret_cast<const u16x4*>((const unsigned short*)In + base);
    #pragma unroll
    for (int j=0;j<4;j++) v[j] = b2f(t[j]);
  }
  float s = v[0]+v[1]+v[2]+v[3];
  float q = v[0]*v[0]+v[1]*v[1]+v[2]*v[2]+v[3]*v[3];
  #pragma unroll
  for (int o=32;o>0;o>>=1){ s += __shfl_xor(s,o,64); q += __shfl_xor(q,o,64); }
  __shared__ float sm[8];
  const int wave = tid>>6, lane = tid&63;
  if (lane==0){ sm[wave] = s; sm[4+wave] = q; }
  __syncthreads();
  s = sm[0]+sm[1]+sm[2]+sm[3];
  q = sm[4]+sm[5]+sm[6]+sm[7];
  const float mean = s*(1.f/1024.f);
  const float rstd = rsqrtf(fmaxf(q*(1.f/1024.f) - mean*mean, 0.f) + 1e-5f);
  #pragma unroll
  for (int j=0;j<4;j++){
    float t2 = (v[j]-mean)*rstd;
    if constexpr (HASGB) t2 = t2*g[tid*4+j] + bb[tid*4+j];
    v[j] = t2;
  }
  if constexpr (OM==OM_F32){
    f32x4 t{v[0],v[1],v[2],v[3]};
    *reinterpret_cast<f32x4*>((float*)Out + base) = t;
  } else if constexpr (OM==OM_BF16){
    u16x4 t{f2b(v[0]),f2b(v[1]),f2b(v[2]),f2b(v[3])};
    *reinterpret_cast<u16x4*>((unsigned short*)Out + base) = t;
  } else {
    u16x4 h{f2b(v[0]),f2b(v[1]),f2b(v[2]),f2b(v[3])};
    u16x4 l{f2b(v[0]-b2f(h[0])),f2b(v[1]-b2f(h[1])),f2b(v[2]-b2f(h[2])),f2b(v[3]-b2f(h[3]))};
    *reinterpret_cast<u16x4*>((unsigned short*)Out + base) = h;
    *reinterpret_cast<u16x4*>(OutL + base) = l;
  }
}

// ---------------------------------------------------------------- weight transpose (layer-batched)
template<bool LO>
__global__ __launch_bounds__(256)
void transpose_cvt_b(const float* __restrict__ W, const float* __restrict__ rs,
                     unsigned short* __restrict__ Wt, unsigned short* __restrict__ Wtlo,
                     int K, int N, size_t wLS, size_t tLS, int dstRowOff)
{
  const int l = blockIdx.z;
  const float* Wl = W + (size_t)l*wLS;
  __shared__ float t[32][33];
  const int tx = threadIdx.x & 31, ty = threadIdx.x >> 5;
  const int n0 = blockIdx.x*32, k0 = blockIdx.y*32;
  #pragma unroll
  for (int j=0;j<4;j++){
    int r = ty + j*8;
    float w = Wl[(size_t)(k0+r)*N + n0 + tx];
    if (rs) w *= rs[l*1024 + k0+r];
    t[r][tx] = w;
  }
  __syncthreads();
  #pragma unroll
  for (int j=0;j<4;j++){
    int r = ty + j*8;
    float w = t[tx][r];
    unsigned short hi = f2b(w);
    size_t di = (size_t)l*tLS + (size_t)(dstRowOff + n0 + r)*K + k0 + tx;
    Wt[di] = hi;
    if constexpr (LO) Wtlo[di] = f2b(w - b2f(hi));
  }
}

__global__ __launch_bounds__(256)
void biaskv_kernel(const float* __restrict__ ln1b, const float* __restrict__ wkv,
                   float* __restrict__ out)
{
  const int l = blockIdx.y;
  const int n = blockIdx.x*256 + threadIdx.x;
  const float* b1 = ln1b + l*1024;
  const float* W  = wkv + (size_t)l*1024*2048;
  float s = 0.f;
  for (int k=0;k<1024;k++) s += b1[k]*W[(size_t)k*2048 + n];
  out[l*2048 + n] = s;
}

__global__ __launch_bounds__(256)
void init_latents(const float* __restrict__ Q, float* __restrict__ L)
{
  size_t idx = ((size_t)blockIdx.x*256 + threadIdx.x)*4;
  int row = (int)(idx >> 10);
  int col = (int)(idx & 1023);
  f32x4 t = *reinterpret_cast<const f32x4*>(Q + (size_t)(row & 15)*1024 + col);
  *reinterpret_cast<f32x4*>(L + idx) = t;
}

__global__ __launch_bounds__(256)
void cvt_f32_bf16(const float* __restrict__ In, unsigned short* __restrict__ Out, size_t n4)
{
  size_t i = (size_t)blockIdx.x*256 + threadIdx.x;
  if (i >= n4) return;
  f32x4 t = *reinterpret_cast<const f32x4*>(In + i*4);
  u16x4 u{f2b(t[0]),f2b(t[1]),f2b(t[2]),f2b(t[3])};
  *reinterpret_cast<u16x4*>(Out + i*4) = u;
}

__global__ __launch_bounds__(256)
void cvt_f32b_pair(const float* __restrict__ In, unsigned short* __restrict__ Oh,
                   unsigned short* __restrict__ Ol)
{
  size_t idx = ((size_t)blockIdx.x*256 + threadIdx.x)*4;
  f32x4 t = *reinterpret_cast<const f32x4*>(In + idx);
  u16x4 h{f2b(t[0]),f2b(t[1]),f2b(t[2]),f2b(t[3])};
  u16x4 l{f2b(t[0]-b2f(h[0])),f2b(t[1]-b2f(h[1])),f2b(t[2]-b2f(h[2])),f2b(t[3]-b2f(h[3]))};
  *reinterpret_cast<u16x4*>(Oh + idx) = h;
  *reinterpret_cast<u16x4*>(Ol + idx) = l;
}

// ---------------------------------------------------------------- attention (R13)
__global__ __launch_bounds__(256)
void attn_kernel(const float* __restrict__ QKVf,
                 const unsigned short* __restrict__ KVX,
                 unsigned short* __restrict__ ATTOh,
                 unsigned short* __restrict__ ATTOl)
{
  __shared__ float qs[16][64];
  __shared__ float ws[16][600];
  const int tid = threadIdx.x;
  const int bh = blockIdx.x;
  const int b = bh >> 4, h = bh & 15;

  {
    int idx = tid*4;
    int qi = idx >> 6, d = idx & 63;
    f32x4 t = *reinterpret_cast<const f32x4*>(QKVf + (size_t)(b*16+qi)*3072 + h*64 + d);
    #pragma unroll
    for (int j=0;j<4;j++) qs[qi][d+j] = 0.125f * t[j];
  }
  __syncthreads();

  {
    const int r0 = tid*2;
    const unsigned short* k0 = KVX + ((size_t)(b*577 + r0)*2048 + h*64);
    const unsigned short* k1 = k0 + 2048;
    float a0[16], a1[16];
    #pragma unroll
    for (int qi=0;qi<16;qi++){ a0[qi]=0.f; a1[qi]=0.f; }
    #pragma unroll 4
    for (int d4=0; d4<16; d4++){
      u16x4 ka = *reinterpret_cast<const u16x4*>(k0 + d4*4);
      u16x4 kb = *reinterpret_cast<const u16x4*>(k1 + d4*4);
      float ka0=b2f(ka[0]), ka1=b2f(ka[1]), ka2=b2f(ka[2]), ka3=b2f(ka[3]);
      float kb0=b2f(kb[0]), kb1=b2f(kb[1]), kb2=b2f(kb[2]), kb3=b2f(kb[3]);
      #pragma unroll
      for (int qi=0;qi<16;qi++){
        f32x4 q4 = *reinterpret_cast<const f32x4*>(&qs[qi][d4*4]);
        a0[qi] += q4[0]*ka0 + q4[1]*ka1 + q4[2]*ka2 + q4[3]*ka3;
        a1[qi] += q4[0]*kb0 + q4[1]*kb1 + q4[2]*kb2 + q4[3]*kb3;
      }
    }
    #pragma unroll
    for (int qi=0;qi<16;qi++){ ws[qi][r0] = a0[qi]; ws[qi][r0+1] = a1[qi]; }
  }
  for (int r = 512 + tid; r < 593; r += 256){
    float a[16];
    #pragma unroll
    for (int qi=0;qi<16;qi++) a[qi] = 0.f;
    if (r < 577){
      const unsigned short* krow = KVX + ((size_t)(b*577 + r)*2048 + h*64);
      #pragma unroll 4
      for (int d4=0; d4<16; d4++){
        u16x4 k4 = *reinterpret_cast<const u16x4*>(krow + d4*4);
        float kf0=b2f(k4[0]), kf1=b2f(k4[1]), kf2=b2f(k4[2]), kf3=b2f(k4[3]);
        #pragma unroll
        for (int qi=0;qi<16;qi++){
          f32x4 q4 = *reinterpret_cast<const f32x4*>(&qs[qi][d4*4]);
          a[qi] += q4[0]*kf0 + q4[1]*kf1 + q4[2]*kf2 + q4[3]*kf3;
        }
      }
    } else {
      const float* krow = QKVf + (size_t)(b*16 + (r-577))*3072 + 1024 + h*64;
      #pragma unroll 4
      for (int d4=0; d4<16; d4++){
        f32x4 k4 = *reinterpret_cast<const f32x4*>(krow + d4*4);
        #pragma unroll
        for (int qi=0;qi<16;qi++){
          f32x4 q4 = *reinterpret_cast<const f32x4*>(&qs[qi][d4*4]);
          a[qi] += q4[0]*k4[0] + q4[1]*k4[1] + q4[2]*k4[2] + q4[3]*k4[3];
        }
      }
    }
    #pragma unroll
    for (int qi=0;qi<16;qi++) ws[qi][r] = a[qi];
  }
  __syncthreads();

  const int wave = tid>>6, lane = tid&63;
  for (int qi = wave; qi < 16; qi += 4){
    float m = -1e30f;
    for (int r = lane; r < 593; r += 64) m = fmaxf(m, ws[qi][r]);
    #pragma unroll
    for (int o=32;o>0;o>>=1) m = fmaxf(m, __shfl_xor(m,o,64));
    float s = 0.f;
    for (int r = lane; r < 593; r += 64){ float e = expf(ws[qi][r]-m); ws[qi][r] = e; s += e; }
    #pragma unroll
    for (int o=32;o>0;o>>=1) s += __shfl_xor(s,o,64);
    float inv = 1.f/s;
    for (int r = lane; r < 593; r += 64) ws[qi][r] *= inv;
  }
  __syncthreads();

  const int d = tid & 63, qg = tid >> 6;
  float o0=0.f,o1=0.f,o2=0.f,o3=0.f;
  for (int rr=0; rr<576; rr+=4){
    f32x4 w0 = *reinterpret_cast<const f32x4*>(&ws[qg   ][rr]);
    f32x4 w1 = *reinterpret_cast<const f32x4*>(&ws[qg+4 ][rr]);
    f32x4 w2 = *reinterpret_cast<const f32x4*>(&ws[qg+8 ][rr]);
    f32x4 w3 = *reinterpret_cast<const f32x4*>(&ws[qg+12][rr]);
    #pragma unroll
    for (int j=0;j<4;j++){
      const unsigned short* vrow = KVX + ((size_t)(b*577 + rr + j)*2048 + 1024 + h*64);
      float v = b2f(vrow[d]);
      o0 += w0[j]*v; o1 += w1[j]*v; o2 += w2[j]*v; o3 += w3[j]*v;
    }
  }
  {
    float v = b2f(KVX[(size_t)(b*577 + 576)*2048 + 1024 + h*64 + d]);
    o0 += ws[qg][576]*v; o1 += ws[qg+4][576]*v; o2 += ws[qg+8][576]*v; o3 += ws[qg+12][576]*v;
  }
  for (int r=577; r<593; r++){
    float v = QKVf[(size_t)(b*16 + (r-577))*3072 + 2048 + h*64 + d];
    o0 += ws[qg][r]*v; o1 += ws[qg+4][r]*v; o2 += ws[qg+8][r]*v; o3 += ws[qg+12][r]*v;
  }
  float ov[4] = {o0,o1,o2,o3};
  #pragma unroll
  for (int j=0;j<4;j++){
    size_t idx = (size_t)(b*16+qg+4*j)*1024 + h*64 + d;
    unsigned short hi = f2b(ov[j]);
    ATTOh[idx] = hi;
    ATTOl[idx] = f2b(ov[j] - b2f(hi));
  }
}

// ---------------------------------------------------------------- host
extern "C" void kernel_launch(void* const* d_in, const int* in_sizes, int n_in,
                              void* d_out, int out_size, void* d_ws, size_t ws_size,
                              hipStream_t stream)
{
  const float* x    = (const float*)d_in[0];
  const float* qry  = (const float*)d_in[1];
  const float* piw  = (const float*)d_in[2];
  const float* pib  = (const float*)d_in[3];
  const float* ln1g = (const float*)d_in[4];
  const float* ln1b = (const float*)d_in[5];
  const float* ln2g = (const float*)d_in[6];
  const float* ln2b = (const float*)d_in[7];
  const float* wq   = (const float*)d_in[8];
  const float* wkv  = (const float*)d_in[9];
  const float* wo   = (const float*)d_in[10];
  const float* ffg  = (const float*)d_in[11];
  const float* ffb  = (const float*)d_in[12];
  const float* w1   = (const float*)d_in[13];
  const float* w2   = (const float*)d_in[14];
  const float* pow_ = (const float*)d_in[15];
  const float* pob  = (const float*)d_in[16];
  const float* ng   = (const float*)d_in[17];
  const float* nb   = (const float*)d_in[18];

  const int MROWS = 64*577;     // 36928; 145 tiles of 256
  char* wsb = (char*)d_ws;
  size_t off = 0;
  auto alloc = [&](size_t bytes)->char*{
    char* p = wsb + off; off = (off + bytes + 255) & ~(size_t)255; return p;
  };
  unsigned short* XB     = (unsigned short*)alloc((size_t)36992*768*2);  // also PART later
  unsigned short* XP     = (unsigned short*)alloc((size_t)36992*1024*2);
  unsigned short* KVX    = (unsigned short*)alloc((size_t)36992*2048*2);
  unsigned short* WpiT   = (unsigned short*)alloc((size_t)1024*768*2);
  unsigned short* WkvTs  = (unsigned short*)alloc((size_t)8*2048*1024*2);
  unsigned short* WqkvT  = (unsigned short*)alloc((size_t)8*3072*1024*2);
  unsigned short* WqkvTl = (unsigned short*)alloc((size_t)8*3072*1024*2);
  unsigned short* WoT    = (unsigned short*)alloc((size_t)8*1024*1024*2);
  unsigned short* WoTl   = (unsigned short*)alloc((size_t)8*1024*1024*2);
  unsigned short* W1T    = (unsigned short*)alloc((size_t)4096*1024*2);
  unsigned short* W1Tl   = (unsigned short*)alloc((size_t)4096*1024*2);
  unsigned short* W2T    = (unsigned short*)alloc((size_t)1024*4096*2);
  unsigned short* W2Tl   = (unsigned short*)alloc((size_t)1024*4096*2);
  float*          BKV    = (float*)alloc((size_t)8*2048*4);
  unsigned short* LTh    = (unsigned short*)alloc((size_t)1024*1024*2);
  unsigned short* LTl    = (unsigned short*)alloc((size_t)1024*1024*2);
  float*          QKVf   = (float*)alloc((size_t)1024*3072*4);
  unsigned short* ATTOh  = (unsigned short*)alloc((size_t)1024*1024*2);
  unsigned short* ATTOl  = (unsigned short*)alloc((size_t)1024*1024*2);
  unsigned short* FFHh   = (unsigned short*)alloc((size_t)1024*4096*2);
  unsigned short* FFHl   = (unsigned short*)alloc((size_t)1024*4096*2);
  unsigned short* LATBh  = (unsigned short*)alloc((size_t)1024*1024*2);
  unsigned short* LATBl  = (unsigned short*)alloc((size_t)1024*1024*2);
  float*          LATF   = (float*)alloc((size_t)1024*1024*4);
  if (off > ws_size) return;  // loud failure
  float* PART = (float*)XB;

  dim3 blk(256);
  dim3 blk5(512);

  // ---- prep
  cvt_f32_bf16<<<dim3((36928*768/4 + 255)/256), blk, 0, stream>>>(x, XB, (size_t)36928*768/4);
  transpose_cvt_b<false><<<dim3(32,24,1), blk, 0, stream>>>(piw, nullptr, WpiT, nullptr, 768, 1024, 0, 0, 0);
  transpose_cvt_b<false><<<dim3(64,32,8), blk, 0, stream>>>(wkv, ln1g, WkvTs, nullptr, 1024, 2048, (size_t)1024*2048, (size_t)2048*1024, 0);
  transpose_cvt_b<true ><<<dim3(32,32,8), blk, 0, stream>>>(wq,  nullptr, WqkvT, WqkvTl, 1024, 1024, (size_t)1024*1024, (size_t)3072*1024, 0);
  transpose_cvt_b<true ><<<dim3(64,32,8), blk, 0, stream>>>(wkv, nullptr, WqkvT, WqkvTl, 1024, 2048, (size_t)1024*2048, (size_t)3072*1024, 1024);
  transpose_cvt_b<true ><<<dim3(32,32,8), blk, 0, stream>>>(wo,  nullptr, WoT, WoTl, 1024, 1024, (size_t)1024*1024, (size_t)1024*1024, 0);
  biaskv_kernel<<<dim3(8,8), blk, 0, stream>>>(ln1b, wkv, BKV);
  init_latents<<<dim3(1024), blk, 0, stream>>>(qry, LATF);

  // xp = x @ proj_in_w + b, then LN in place -> xhat (bf16)
  gemm3<<<dim3(145*4), blk5, 0, stream>>>(XB, WpiT, pib, XP, MROWS, 1024, 768, 4);
  ln_rows<false,OM_BF16,false><<<dim3(MROWS), blk, 0, stream>>>(XP, XP, nullptr, nullptr, nullptr);

  // lt for layer 0
  ln_rows<true,OM_SPLIT,true><<<dim3(1024), blk, 0, stream>>>(LATF, LTh, LTl, ln2g, ln2b);

  for (int l=0; l<8; l++){
    transpose_cvt_b<true><<<dim3(128,32,1), blk, 0, stream>>>(w1 + (size_t)l*1024*4096, nullptr, W1T, W1Tl, 1024, 4096, 0, 0, 0);
    transpose_cvt_b<true><<<dim3(32,128,1), blk, 0, stream>>>(w2 + (size_t)l*4096*1024, nullptr, W2T, W2Tl, 4096, 1024, 0, 0, 0);

    // qkv_lt = lt @ [Wq|Wkv]  (split, fp32-accurate)
    gemm_sp2<EPI_F32><<<dim3(16*48), blk, 0, stream>>>(
        LTh, LTl, WqkvT + (size_t)l*3072*1024, WqkvTl + (size_t)l*3072*1024,
        nullptr, nullptr, QKVf, nullptr, 1024, 3072, 1024, 48);
    // kv_x = xhat @ (g1-scaled Wkv) + b1@Wkv
    gemm3<<<dim3(145*8), blk5, 0, stream>>>(
        XP, WkvTs + (size_t)l*2048*1024, BKV + l*2048, KVX, MROWS, 2048, 1024, 8);
    // attention
    attn_kernel<<<dim3(1024), blk, 0, stream>>>(QKVf, KVX, ATTOh, ATTOl);
    // latents += o @ Wo  (split)
    gemm_sp2<EPI_RESF32><<<dim3(16*16), blk, 0, stream>>>(
        ATTOh, ATTOl, WoT + (size_t)l*1024*1024, WoTl + (size_t)l*1024*1024,
        nullptr, LATF, LATF, nullptr, 1024, 1024, 1024, 16);
    // FF (split)
    ln_rows<true,OM_SPLIT,true><<<dim3(1024), blk, 0, stream>>>(LATF, LTh, LTl, ffg + l*1024, ffb + l*1024);
    gemm_sp2<EPI_GELU><<<dim3(16*64), blk, 0, stream>>>(
        LTh, LTl, W1T, W1Tl, nullptr, nullptr, FFHh, FFHl, 1024, 4096, 1024, 64);
    gemm_spk<<<dim3(4*16*16), blk, 0, stream>>>(
        FFHh, FFHl, W2T, W2Tl, PART, 1024, 1024, 4096, 1024, 16);
    if (l < 7){
      reduce_ln<<<dim3(1024), blk, 0, stream>>>(PART, LATF, LTh, LTl, ln2g + (l+1)*1024, ln2b + (l+1)*1024);
    } else {
      reduce4_res<<<dim3(1024), blk, 0, stream>>>(PART, LATF);
    }
  }

  // out = LN(latents @ Wpo + b, nout)
  transpose_cvt_b<true><<<dim3(32,32,1), blk, 0, stream>>>(pow_, nullptr, W1T, W1Tl, 1024, 1024, 0, 0, 0);
  cvt_f32b_pair<<<dim3(1024), blk, 0, stream>>>(LATF, LATBh, LATBl);
  gemm_sp2<EPI_F32><<<dim3(16*16), blk, 0, stream>>>(
      LATBh, LATBl, W1T, W1Tl, pob, nullptr, QKVf, nullptr, 1024, 1024, 1024, 16);
  ln_rows<true,OM_F32,true><<<dim3(1024), blk, 0, stream>>>(QKVf, d_out, nullptr, ng, nb);
}